// Round 1
// baseline (8200.064 us; speedup 1.0000x reference)
//
#include <hip/hip_runtime.h>
#include <math.h>

#define BB 4
#define TT 2048
#define DD 1024
#define HH 128
#define EPSF 1e-6f
#define BT (BB*TT)   // 8192

// ---------------------------------------------------------------------------
// Projection: P[bt][h] = sum_d x[bt][d] * W[h][d] + bias[h]
// gridDim.x = BT/64, gridDim.y = 3 (q,k,v). block = 256.
// ---------------------------------------------------------------------------
__global__ __launch_bounds__(256) void proj_kernel(
    const float* __restrict__ x,
    const float* __restrict__ Wq, const float* __restrict__ bq,
    const float* __restrict__ Wk, const float* __restrict__ bk,
    const float* __restrict__ Wv, const float* __restrict__ bv,
    float* __restrict__ Q, float* __restrict__ K, float* __restrict__ V)
{
    const int which = blockIdx.y;
    const float* W    = (which == 0) ? Wq : (which == 1) ? Wk : Wv;
    const float* bias = (which == 0) ? bq : (which == 1) ? bk : bv;
    float* P          = (which == 0) ? Q  : (which == 1) ? K  : V;

    const int row0 = blockIdx.x * 64;

    __shared__ float xT[32][68];
    __shared__ float wT[32][132];

    const int tid = threadIdx.x;
    const int tx = tid & 15;
    const int ty = tid >> 4;

    float acc[4][8];
    #pragma unroll
    for (int i = 0; i < 4; i++)
        #pragma unroll
        for (int j = 0; j < 8; j++) acc[i][j] = 0.f;

    for (int k0 = 0; k0 < DD; k0 += 32) {
        #pragma unroll
        for (int l = 0; l < 2; l++) {
            int f = tid + l * 256;
            int r = f >> 3;
            int cg = f & 7;
            float4 v = *(const float4*)(x + (size_t)(row0 + r) * DD + k0 + cg * 4);
            xT[cg*4+0][r] = v.x; xT[cg*4+1][r] = v.y;
            xT[cg*4+2][r] = v.z; xT[cg*4+3][r] = v.w;
        }
        #pragma unroll
        for (int l = 0; l < 4; l++) {
            int f = tid + l * 256;
            int h = f >> 3;
            int cg = f & 7;
            float4 v = *(const float4*)(W + (size_t)h * DD + k0 + cg * 4);
            wT[cg*4+0][h] = v.x; wT[cg*4+1][h] = v.y;
            wT[cg*4+2][h] = v.z; wT[cg*4+3][h] = v.w;
        }
        __syncthreads();
        #pragma unroll
        for (int kk = 0; kk < 32; kk++) {
            float4 xv = *(const float4*)&xT[kk][ty * 4];
            float4 w0 = *(const float4*)&wT[kk][tx * 8];
            float4 w1 = *(const float4*)&wT[kk][tx * 8 + 4];
            float xa[4] = {xv.x, xv.y, xv.z, xv.w};
            float wa[8] = {w0.x, w0.y, w0.z, w0.w, w1.x, w1.y, w1.z, w1.w};
            #pragma unroll
            for (int i = 0; i < 4; i++)
                #pragma unroll
                for (int j = 0; j < 8; j++)
                    acc[i][j] += xa[i] * wa[j];
        }
        __syncthreads();
    }

    #pragma unroll
    for (int i = 0; i < 4; i++) {
        int row = row0 + ty * 4 + i;
        #pragma unroll
        for (int j = 0; j < 8; j++) acc[i][j] += bias[tx * 8 + j];
        float4 o0 = {acc[i][0], acc[i][1], acc[i][2], acc[i][3]};
        float4 o1 = {acc[i][4], acc[i][5], acc[i][6], acc[i][7]};
        *(float4*)(P + (size_t)row * HH + tx * 8)     = o0;
        *(float4*)(P + (size_t)row * HH + tx * 8 + 4) = o1;
    }
}

// ---------------------------------------------------------------------------
// Sequential scan, latency-optimized v2: ONE barrier per step.
// grid = B blocks, block = 512 threads. Thread owns A[r][c0..c0+31],
// M[r][c0..c0+31] in registers, r = tid>>2, c0 = (tid&3)*32.
//
// All threads are symmetric (no producer wave): each thread loads k,q at its
// own 32 columns (plus v[r]) straight from global into registers; ||k||^2 and
// k.q are quad-reduced (quads span all 128 columns). The ONLY cross-thread
// communication is the Aus broadcast (z~raw = (A k)[r]) through LDS, guarded
// by a single __syncthreads per step. denom = 1 + u^T z~ is recomputed
// per-thread AFTER the barrier from in-register k and the Aus values read
// anyway. rn = 1/(||k||+eps) is folded into the scalars cA/cM/denom so the
// sqrt/rcp chain overlaps the LDS read latency instead of preceding the
// barrier. Aus is padded (groups of 32 at stride 36) so the 4 quad-column
// float4 reads hit disjoint banks: conflict-free.
// ---------------------------------------------------------------------------
__global__ __launch_bounds__(512) void scan_kernel(
    const float* __restrict__ Q, const float* __restrict__ K,
    const float* __restrict__ V, float* __restrict__ O)
{
    const int b   = blockIdx.x;
    const int tid = threadIdx.x;
    const int r   = tid >> 2;     // row 0..127
    const int q4  = tid & 3;      // column quarter
    const int c0  = q4 * 32;

    // col c of step-buf lives at [buf][(c>>5)*36 + (c&31)]: 16B-aligned float4
    // groups, group stride 36 floats -> banks (36*q4)%32 = {0,4,8,12} disjoint.
    __shared__ float Aus[2][4 * 36];

    float Areg[32], Mreg[32];
    #pragma unroll
    for (int j = 0; j < 32; j++) {
        Mreg[j] = 0.f;
        Areg[j] = (c0 + j == r) ? 1.0f : 0.0f;   // A0 = I / lambda0
    }

    const float* Qb = Q + (size_t)b * TT * HH;
    const float* Kb = K + (size_t)b * TT * HH;
    const float* Vb = V + (size_t)b * TT * HH;
    float*       Ob = O + (size_t)b * TT * HH;

    const int woff = (r >> 5) * 36 + (r & 31);   // my row's slot in Aus

    // prologue: load t=0
    float4 kk[8], qq[8];
    #pragma unroll
    for (int j = 0; j < 8; j++) {
        kk[j] = *(const float4*)(Kb + c0 + 4 * j);
        qq[j] = *(const float4*)(Qb + c0 + 4 * j);
    }
    float vr = Vb[r];

    for (int t = 0; t < TT; t++) {
        const int buf = t & 1;

        // --- praw = (A k)[r] partial over my 32 cols (critical path from
        //     previous step's A update). 2 accumulators for ILP.
        float pa0 = 0.f, pa1 = 0.f;
        #pragma unroll
        for (int j = 0; j < 8; j += 2) {
            float4 k0 = kk[j], k1 = kk[j + 1];
            pa0 += Areg[4*j+0]*k0.x + Areg[4*j+1]*k0.y
                 + Areg[4*j+2]*k0.z + Areg[4*j+3]*k0.w;
            pa1 += Areg[4*j+4]*k1.x + Areg[4*j+5]*k1.y
                 + Areg[4*j+6]*k1.z + Areg[4*j+7]*k1.w;
        }
        float praw = pa0 + pa1;
        praw += __shfl_xor(praw, 1);
        praw += __shfl_xor(praw, 2);          // all 4 quad lanes hold (A k)[r]
        if ((tid & 3) == 0) Aus[buf][woff] = praw;

        // --- prefetch t+1 (k,q at my columns; v[r]) — consumed next step
        float4 kn[8], qn[8];
        float vn = 0.f;
        if (t + 1 < TT) {
            const float* kp = Kb + (size_t)(t + 1) * HH + c0;
            const float* qp = Qb + (size_t)(t + 1) * HH + c0;
            #pragma unroll
            for (int j = 0; j < 8; j++) {
                kn[j] = *(const float4*)(kp + 4 * j);
                qn[j] = *(const float4*)(qp + 4 * j);
            }
            vn = Vb[(size_t)(t + 1) * HH + r];
        }

        // --- ||k||^2 and k.q partials (independent of A)
        float p2 = 0.f, pkq = 0.f;
        #pragma unroll
        for (int j = 0; j < 8; j++) {
            float4 kv = kk[j], qv = qq[j];
            p2  += kv.x*kv.x + kv.y*kv.y + kv.z*kv.z + kv.w*kv.w;
            pkq += kv.x*qv.x + kv.y*qv.y + kv.z*qv.z + kv.w*qv.w;
        }

        __syncthreads();   // the ONE barrier: Aus[buf] ready

        // --- read z~raw vector at my columns (conflict-free padded layout)
        float4 av[8];
        #pragma unroll
        for (int j = 0; j < 8; j++)
            av[j] = *(const float4*)&Aus[buf][q4 * 36 + 4 * j];

        // overlap with LDS latency: finish scalar reductions
        p2  += __shfl_xor(p2, 1);  p2  += __shfl_xor(p2, 2);
        pkq += __shfl_xor(pkq, 1); pkq += __shfl_xor(pkq, 2);
        const float rn = 1.0f / (sqrtf(p2) + EPSF);

        // --- denom = 1 + u^T z~ = 1 + rn^2 * (k . z~raw), recomputed locally
        float pd0 = 0.f, pd1 = 0.f;
        #pragma unroll
        for (int j = 0; j < 8; j += 2) {
            float4 a0 = av[j], k0 = kk[j];
            float4 a1 = av[j + 1], k1 = kk[j + 1];
            pd0 += a0.x*k0.x + a0.y*k0.y + a0.z*k0.z + a0.w*k0.w;
            pd1 += a1.x*k1.x + a1.y*k1.y + a1.z*k1.z + a1.w*k1.w;
        }
        float pd = pd0 + pd1;
        pd += __shfl_xor(pd, 1);
        pd += __shfl_xor(pd, 2);

        const float rn2   = rn * rn;
        const float denom = 1.0f + rn2 * pd;
        const float inv_d = 1.0f / denom;
        // A[r][c] -= z~[r] z~[c]/denom = (rn^2 praw_r inv_d) * praw_c
        const float cA = praw * rn2 * inv_d;
        // M[r][c] += v[r] * alpha[c], alpha = s * rn * praw_c * inv_d
        const float cM = vr * pkq * rn * inv_d;

        // --- fused rank-1 updates + o = (M_new q)[r] partial
        float o0 = 0.f, o1 = 0.f, o2 = 0.f, o3 = 0.f;
        #pragma unroll
        for (int j = 0; j < 8; j++) {
            float4 a = av[j], qv = qq[j];
            Areg[4*j+0] = fmaf(-cA, a.x, Areg[4*j+0]);
            Mreg[4*j+0] = fmaf( cM, a.x, Mreg[4*j+0]);
            o0 = fmaf(Mreg[4*j+0], qv.x, o0);
            Areg[4*j+1] = fmaf(-cA, a.y, Areg[4*j+1]);
            Mreg[4*j+1] = fmaf( cM, a.y, Mreg[4*j+1]);
            o1 = fmaf(Mreg[4*j+1], qv.y, o1);
            Areg[4*j+2] = fmaf(-cA, a.z, Areg[4*j+2]);
            Mreg[4*j+2] = fmaf( cM, a.z, Mreg[4*j+2]);
            o2 = fmaf(Mreg[4*j+2], qv.z, o2);
            Areg[4*j+3] = fmaf(-cA, a.w, Areg[4*j+3]);
            Mreg[4*j+3] = fmaf( cM, a.w, Mreg[4*j+3]);
            o3 = fmaf(Mreg[4*j+3], qv.w, o3);
        }
        float o = (o0 + o1) + (o2 + o3);
        o += __shfl_xor(o, 1);
        o += __shfl_xor(o, 2);
        if ((tid & 3) == 0) Ob[(size_t)t * HH + r] = o;

        // rotate prefetched regs
        #pragma unroll
        for (int j = 0; j < 8; j++) { kk[j] = kn[j]; qq[j] = qn[j]; }
        vr = vn;
        // No second barrier needed: next step writes Aus[buf^1]; the next
        // step's __syncthreads separates this step's Aus[buf] reads from the
        // t+2 writes to Aus[buf].
    }
}

// ---------------------------------------------------------------------------
// Output: out[bt][d] = sum_h O[bt][h] * Wo[d][h] + bo[d]
// ---------------------------------------------------------------------------
__global__ __launch_bounds__(256) void out_kernel(
    const float* __restrict__ O, const float* __restrict__ Wo,
    const float* __restrict__ bo, float* __restrict__ out)
{
    const int row0 = blockIdx.x * 64;
    const int d0   = blockIdx.y * 128;

    __shared__ float oT[32][68];
    __shared__ float woT[32][132];

    const int tid = threadIdx.x;
    const int tx = tid & 15;
    const int ty = tid >> 4;

    float acc[4][8];
    #pragma unroll
    for (int i = 0; i < 4; i++)
        #pragma unroll
        for (int j = 0; j < 8; j++) acc[i][j] = 0.f;

    for (int k0 = 0; k0 < HH; k0 += 32) {
        #pragma unroll
        for (int l = 0; l < 2; l++) {
            int f = tid + l * 256;
            int r = f >> 3;
            int cg = f & 7;
            float4 v = *(const float4*)(O + (size_t)(row0 + r) * HH + k0 + cg * 4);
            oT[cg*4+0][r] = v.x; oT[cg*4+1][r] = v.y;
            oT[cg*4+2][r] = v.z; oT[cg*4+3][r] = v.w;
        }
        #pragma unroll
        for (int l = 0; l < 4; l++) {
            int f = tid + l * 256;
            int d = f >> 3;
            int cg = f & 7;
            float4 v = *(const float4*)(Wo + (size_t)(d0 + d) * HH + k0 + cg * 4);
            woT[cg*4+0][d] = v.x; woT[cg*4+1][d] = v.y;
            woT[cg*4+2][d] = v.z; woT[cg*4+3][d] = v.w;
        }
        __syncthreads();
        #pragma unroll
        for (int kk = 0; kk < 32; kk++) {
            float4 ov = *(const float4*)&oT[kk][ty * 4];
            float4 w0 = *(const float4*)&woT[kk][tx * 8];
            float4 w1 = *(const float4*)&woT[kk][tx * 8 + 4];
            float oa[4] = {ov.x, ov.y, ov.z, ov.w};
            float wa[8] = {w0.x, w0.y, w0.z, w0.w, w1.x, w1.y, w1.z, w1.w};
            #pragma unroll
            for (int i = 0; i < 4; i++)
                #pragma unroll
                for (int j = 0; j < 8; j++)
                    acc[i][j] += oa[i] * wa[j];
        }
        __syncthreads();
    }

    #pragma unroll
    for (int i = 0; i < 4; i++) {
        int row = row0 + ty * 4 + i;
        #pragma unroll
        for (int j = 0; j < 8; j++) acc[i][j] += bo[d0 + tx * 8 + j];
        float4 o0 = {acc[i][0], acc[i][1], acc[i][2], acc[i][3]};
        float4 o1 = {acc[i][4], acc[i][5], acc[i][6], acc[i][7]};
        *(float4*)(out + (size_t)row * DD + d0 + tx * 8)     = o0;
        *(float4*)(out + (size_t)row * DD + d0 + tx * 8 + 4) = o1;
    }
}

extern "C" void kernel_launch(void* const* d_in, const int* in_sizes, int n_in,
                              void* d_out, int out_size, void* d_ws, size_t ws_size,
                              hipStream_t stream) {
    const float* x  = (const float*)d_in[0];
    const float* Wq = (const float*)d_in[1];
    const float* bq = (const float*)d_in[2];
    const float* Wk = (const float*)d_in[3];
    const float* bk = (const float*)d_in[4];
    const float* Wv = (const float*)d_in[5];
    const float* bv = (const float*)d_in[6];
    const float* Wo = (const float*)d_in[7];
    const float* bo = (const float*)d_in[8];
    float* out = (float*)d_out;

    float* ws = (float*)d_ws;
    float* Q = ws;
    float* K = ws + (size_t)BT * HH;
    float* V = ws + (size_t)2 * BT * HH;
    float* O = ws + (size_t)3 * BT * HH;

    dim3 pgrid(BT / 64, 3);
    proj_kernel<<<pgrid, 256, 0, stream>>>(x, Wq, bq, Wk, bk, Wv, bv, Q, K, V);

    scan_kernel<<<BB, 512, 0, stream>>>(Q, K, V, O);

    dim3 ogrid(BT / 64, DD / 128);
    out_kernel<<<ogrid, 256, 0, stream>>>(O, Wo, bo, out);
}

// Round 2
// 3184.981 us; speedup vs baseline: 2.5746x; 2.5746x over previous
//
#include <hip/hip_runtime.h>
#include <math.h>

#define BB 4
#define TT 2048
#define DD 1024
#define HH 128
#define EPSF 1e-6f
#define BT (BB*TT)   // 8192

// ---------------------------------------------------------------------------
// Projection: P[bt][h] = sum_d x[bt][d] * W[h][d] + bias[h]
// gridDim.x = BT/64, gridDim.y = 3 (q,k,v). block = 256.
// ---------------------------------------------------------------------------
__global__ __launch_bounds__(256) void proj_kernel(
    const float* __restrict__ x,
    const float* __restrict__ Wq, const float* __restrict__ bq,
    const float* __restrict__ Wk, const float* __restrict__ bk,
    const float* __restrict__ Wv, const float* __restrict__ bv,
    float* __restrict__ Q, float* __restrict__ K, float* __restrict__ V)
{
    const int which = blockIdx.y;
    const float* W    = (which == 0) ? Wq : (which == 1) ? Wk : Wv;
    const float* bias = (which == 0) ? bq : (which == 1) ? bk : bv;
    float* P          = (which == 0) ? Q  : (which == 1) ? K  : V;

    const int row0 = blockIdx.x * 64;

    __shared__ float xT[32][68];
    __shared__ float wT[32][132];

    const int tid = threadIdx.x;
    const int tx = tid & 15;
    const int ty = tid >> 4;

    float acc[4][8];
    #pragma unroll
    for (int i = 0; i < 4; i++)
        #pragma unroll
        for (int j = 0; j < 8; j++) acc[i][j] = 0.f;

    for (int k0 = 0; k0 < DD; k0 += 32) {
        #pragma unroll
        for (int l = 0; l < 2; l++) {
            int f = tid + l * 256;
            int r = f >> 3;
            int cg = f & 7;
            float4 v = *(const float4*)(x + (size_t)(row0 + r) * DD + k0 + cg * 4);
            xT[cg*4+0][r] = v.x; xT[cg*4+1][r] = v.y;
            xT[cg*4+2][r] = v.z; xT[cg*4+3][r] = v.w;
        }
        #pragma unroll
        for (int l = 0; l < 4; l++) {
            int f = tid + l * 256;
            int h = f >> 3;
            int cg = f & 7;
            float4 v = *(const float4*)(W + (size_t)h * DD + k0 + cg * 4);
            wT[cg*4+0][h] = v.x; wT[cg*4+1][h] = v.y;
            wT[cg*4+2][h] = v.z; wT[cg*4+3][h] = v.w;
        }
        __syncthreads();
        #pragma unroll
        for (int kk = 0; kk < 32; kk++) {
            float4 xv = *(const float4*)&xT[kk][ty * 4];
            float4 w0 = *(const float4*)&wT[kk][tx * 8];
            float4 w1 = *(const float4*)&wT[kk][tx * 8 + 4];
            float xa[4] = {xv.x, xv.y, xv.z, xv.w};
            float wa[8] = {w0.x, w0.y, w0.z, w0.w, w1.x, w1.y, w1.z, w1.w};
            #pragma unroll
            for (int i = 0; i < 4; i++)
                #pragma unroll
                for (int j = 0; j < 8; j++)
                    acc[i][j] += xa[i] * wa[j];
        }
        __syncthreads();
    }

    #pragma unroll
    for (int i = 0; i < 4; i++) {
        int row = row0 + ty * 4 + i;
        #pragma unroll
        for (int j = 0; j < 8; j++) acc[i][j] += bias[tx * 8 + j];
        float4 o0 = {acc[i][0], acc[i][1], acc[i][2], acc[i][3]};
        float4 o1 = {acc[i][4], acc[i][5], acc[i][6], acc[i][7]};
        *(float4*)(P + (size_t)row * HH + tx * 8)     = o0;
        *(float4*)(P + (size_t)row * HH + tx * 8 + 4) = o1;
    }
}

// ---------------------------------------------------------------------------
// Sequential scan v3: ONE barrier per step + cooperative k/q/v staging.
// grid = B blocks, block = 512 threads. Thread owns A[r][c0..c0+31],
// M[r][c0..c0+31] in registers, r = tid>>2, c0 = (tid&3)*32.
//
// v2 lesson: per-thread redundant global loads (17 VMEM instr/thread/step)
// were the regression. Here only 96 loader threads touch global per step
// (3 wave-instructions for the whole block): tid<32 loads k, 32..63 q,
// 64..95 v, one float4 each, held in registers one step ahead and written
// to a double-buffered padded LDS staging buffer in phase A. All threads
// refill their kk/qq/vr registers from LDS post-barrier INTO THE SAME
// registers (no second copy -> no spill). LDS reads are 16-way broadcast,
// 4 unique float4 addresses on disjoint banks: conflict-free.
//
// Padded layout: column c lives at float offset (c>>5)*36 + (c&31);
// group stride 36 -> q4*36 % 32 = {0,4,8,12}, disjoint bank quads.
//
// Quad-only reductions (__shfl_xor 1,2) compile to DPP quad_perm: cheap
// VALU, no DS pipe. denom recomputed per-thread after the barrier from
// in-register k and the Aus values read anyway; rn computed pre-barrier.
// ---------------------------------------------------------------------------
__global__ __launch_bounds__(512, 1) void scan_kernel(
    const float* __restrict__ Q, const float* __restrict__ K,
    const float* __restrict__ V, float* __restrict__ O)
{
    const int b   = blockIdx.x;
    const int tid = threadIdx.x;
    const int r   = tid >> 2;     // row 0..127
    const int q4  = tid & 3;      // column quarter
    const int c0  = q4 * 32;

    __shared__ float Aus[2][4 * 36];        // (A k) broadcast, padded
    __shared__ float kq[2][2][4 * 36];      // [buf][0=k,1=q], padded
    __shared__ float vbuf[2][128];          // v, linear

    float Areg[32], Mreg[32];
    #pragma unroll
    for (int j = 0; j < 32; j++) {
        Mreg[j] = 0.f;
        Areg[j] = (c0 + j == r) ? 1.0f : 0.0f;   // A0 = I / lambda0
    }

    const float* Qb = Q + (size_t)b * TT * HH;
    const float* Kb = K + (size_t)b * TT * HH;
    const float* Vb = V + (size_t)b * TT * HH;
    float*       Ob = O + (size_t)b * TT * HH;

    const int woff = (r >> 5) * 36 + (r & 31);   // my row's slot in Aus

    // loader role: 96 threads, one float4 each per step
    const bool ldr   = tid < 96;
    const int  which = tid >> 5;                 // 0=k 1=q 2=v
    const int  l32   = tid & 31;
    const float* src = (which == 0) ? Kb : (which == 1) ? Qb : Vb;
    const int  lpoff = (l32 >> 3) * 36 + (l32 & 7) * 4;  // padded f4 offset

    float4 pld = {0.f, 0.f, 0.f, 0.f};

    // prologue: stage t=0, prefetch t=1
    if (ldr) {
        float4 d0 = *(const float4*)(src + l32 * 4);
        if (which < 2) *(float4*)&kq[0][which][lpoff] = d0;
        else           *(float4*)&vbuf[0][l32 * 4]    = d0;
        pld = *(const float4*)(src + (size_t)HH + l32 * 4);
    }
    __syncthreads();

    float4 kk[8], qq[8];
    #pragma unroll
    for (int j = 0; j < 8; j++) {
        kk[j] = *(const float4*)&kq[0][0][q4 * 36 + 4 * j];
        qq[j] = *(const float4*)&kq[0][1][q4 * 36 + 4 * j];
    }
    float vr = vbuf[0][r];

    for (int t = 0; t < TT; t++) {
        const int buf  = t & 1;
        const int nbuf = buf ^ 1;

        // --- phase A: praw = (A k)[r] partial over my 32 cols
        float pa0 = 0.f, pa1 = 0.f;
        #pragma unroll
        for (int j = 0; j < 8; j += 2) {
            float4 k0 = kk[j], k1 = kk[j + 1];
            pa0 += Areg[4*j+0]*k0.x + Areg[4*j+1]*k0.y
                 + Areg[4*j+2]*k0.z + Areg[4*j+3]*k0.w;
            pa1 += Areg[4*j+4]*k1.x + Areg[4*j+5]*k1.y
                 + Areg[4*j+6]*k1.z + Areg[4*j+7]*k1.w;
        }
        float praw = pa0 + pa1;
        praw += __shfl_xor(praw, 1);
        praw += __shfl_xor(praw, 2);          // quad lanes all hold (A k)[r]
        if (q4 == 0) Aus[buf][woff] = praw;

        // stage t+1 into LDS; issue global load for t+2
        if (ldr && t + 1 < TT) {
            if (which < 2) *(float4*)&kq[nbuf][which][lpoff] = pld;
            else           *(float4*)&vbuf[nbuf][l32 * 4]    = pld;
            if (t + 2 < TT)
                pld = *(const float4*)(src + (size_t)(t + 2) * HH + l32 * 4);
        }

        // --- ||k||^2 and k.q (independent of A): reduce + rn pre-barrier
        float p2 = 0.f, pkq = 0.f;
        #pragma unroll
        for (int j = 0; j < 8; j++) {
            float4 kv = kk[j], qv = qq[j];
            p2  += kv.x*kv.x + kv.y*kv.y + kv.z*kv.z + kv.w*kv.w;
            pkq += kv.x*qv.x + kv.y*qv.y + kv.z*qv.z + kv.w*qv.w;
        }
        p2  += __shfl_xor(p2, 1);  p2  += __shfl_xor(p2, 2);
        pkq += __shfl_xor(pkq, 1); pkq += __shfl_xor(pkq, 2);
        const float rn = 1.0f / (sqrtf(p2) + EPSF);

        __syncthreads();   // the ONE barrier: Aus[buf] + kq/vbuf[nbuf] ready

        // --- read z~raw at my columns (conflict-free padded layout)
        float4 av[8];
        #pragma unroll
        for (int j = 0; j < 8; j++)
            av[j] = *(const float4*)&Aus[buf][q4 * 36 + 4 * j];

        // --- denom = 1 + rn^2 * (k . z~raw), recomputed locally
        float pd0 = 0.f, pd1 = 0.f;
        #pragma unroll
        for (int j = 0; j < 8; j += 2) {
            float4 a0 = av[j], k0 = kk[j];
            float4 a1 = av[j + 1], k1 = kk[j + 1];
            pd0 += a0.x*k0.x + a0.y*k0.y + a0.z*k0.z + a0.w*k0.w;
            pd1 += a1.x*k1.x + a1.y*k1.y + a1.z*k1.z + a1.w*k1.w;
        }
        float pd = pd0 + pd1;
        pd += __shfl_xor(pd, 1);
        pd += __shfl_xor(pd, 2);

        // kk dead -> refill for t+1 from LDS (same registers, no spill)
        #pragma unroll
        for (int j = 0; j < 8; j++)
            kk[j] = *(const float4*)&kq[nbuf][0][q4 * 36 + 4 * j];

        const float rn2   = rn * rn;
        const float inv_d = 1.0f / (1.0f + rn2 * pd);
        const float cA = praw * rn2 * inv_d;      // A -= cA * praw_c
        const float cM = vr * pkq * rn * inv_d;   // M += cM * praw_c

        // --- fused rank-1 updates + o = (M_new q)[r] partial
        float o0 = 0.f, o1 = 0.f, o2 = 0.f, o3 = 0.f;
        #pragma unroll
        for (int j = 0; j < 8; j++) {
            float4 a = av[j], qv = qq[j];
            Areg[4*j+0] = fmaf(-cA, a.x, Areg[4*j+0]);
            Mreg[4*j+0] = fmaf( cM, a.x, Mreg[4*j+0]);
            o0 = fmaf(Mreg[4*j+0], qv.x, o0);
            Areg[4*j+1] = fmaf(-cA, a.y, Areg[4*j+1]);
            Mreg[4*j+1] = fmaf( cM, a.y, Mreg[4*j+1]);
            o1 = fmaf(Mreg[4*j+1], qv.y, o1);
            Areg[4*j+2] = fmaf(-cA, a.z, Areg[4*j+2]);
            Mreg[4*j+2] = fmaf( cM, a.z, Mreg[4*j+2]);
            o2 = fmaf(Mreg[4*j+2], qv.z, o2);
            Areg[4*j+3] = fmaf(-cA, a.w, Areg[4*j+3]);
            Mreg[4*j+3] = fmaf( cM, a.w, Mreg[4*j+3]);
            o3 = fmaf(Mreg[4*j+3], qv.w, o3);
        }
        float o = (o0 + o1) + (o2 + o3);
        o += __shfl_xor(o, 1);
        o += __shfl_xor(o, 2);
        if (q4 == 0) Ob[(size_t)t * HH + r] = o;

        // qq, vr dead -> refill for t+1
        #pragma unroll
        for (int j = 0; j < 8; j++)
            qq[j] = *(const float4*)&kq[nbuf][1][q4 * 36 + 4 * j];
        vr = vbuf[nbuf][r];
        // Next write to slot nbuf / Aus[buf] happens in step t+2 phase A,
        // separated from these reads by step t+1's barrier.
    }
}

// ---------------------------------------------------------------------------
// Output: out[bt][d] = sum_h O[bt][h] * Wo[d][h] + bo[d]
// ---------------------------------------------------------------------------
__global__ __launch_bounds__(256) void out_kernel(
    const float* __restrict__ O, const float* __restrict__ Wo,
    const float* __restrict__ bo, float* __restrict__ out)
{
    const int row0 = blockIdx.x * 64;
    const int d0   = blockIdx.y * 128;

    __shared__ float oT[32][68];
    __shared__ float woT[32][132];

    const int tid = threadIdx.x;
    const int tx = tid & 15;
    const int ty = tid >> 4;

    float acc[4][8];
    #pragma unroll
    for (int i = 0; i < 4; i++)
        #pragma unroll
        for (int j = 0; j < 8; j++) acc[i][j] = 0.f;

    for (int k0 = 0; k0 < HH; k0 += 32) {
        #pragma unroll
        for (int l = 0; l < 2; l++) {
            int f = tid + l * 256;
            int r = f >> 3;
            int cg = f & 7;
            float4 v = *(const float4*)(O + (size_t)(row0 + r) * HH + k0 + cg * 4);
            oT[cg*4+0][r] = v.x; oT[cg*4+1][r] = v.y;
            oT[cg*4+2][r] = v.z; oT[cg*4+3][r] = v.w;
        }
        #pragma unroll
        for (int l = 0; l < 4; l++) {
            int f = tid + l * 256;
            int d = f >> 3;
            int cg = f & 7;
            float4 v = *(const float4*)(Wo + (size_t)(d0 + d) * HH + k0 + cg * 4);
            woT[cg*4+0][d] = v.x; woT[cg*4+1][d] = v.y;
            woT[cg*4+2][d] = v.z; woT[cg*4+3][d] = v.w;
        }
        __syncthreads();
        #pragma unroll
        for (int kk = 0; kk < 32; kk++) {
            float4 ov = *(const float4*)&oT[kk][ty * 4];
            float4 w0 = *(const float4*)&woT[kk][tx * 8];
            float4 w1 = *(const float4*)&woT[kk][tx * 8 + 4];
            float oa[4] = {ov.x, ov.y, ov.z, ov.w};
            float wa[8] = {w0.x, w0.y, w0.z, w0.w, w1.x, w1.y, w1.z, w1.w};
            #pragma unroll
            for (int i = 0; i < 4; i++)
                #pragma unroll
                for (int j = 0; j < 8; j++)
                    acc[i][j] += oa[i] * wa[j];
        }
        __syncthreads();
    }

    #pragma unroll
    for (int i = 0; i < 4; i++) {
        int row = row0 + ty * 4 + i;
        #pragma unroll
        for (int j = 0; j < 8; j++) acc[i][j] += bo[d0 + tx * 8 + j];
        float4 o0 = {acc[i][0], acc[i][1], acc[i][2], acc[i][3]};
        float4 o1 = {acc[i][4], acc[i][5], acc[i][6], acc[i][7]};
        *(float4*)(out + (size_t)row * DD + d0 + tx * 8)     = o0;
        *(float4*)(out + (size_t)row * DD + d0 + tx * 8 + 4) = o1;
    }
}

extern "C" void kernel_launch(void* const* d_in, const int* in_sizes, int n_in,
                              void* d_out, int out_size, void* d_ws, size_t ws_size,
                              hipStream_t stream) {
    const float* x  = (const float*)d_in[0];
    const float* Wq = (const float*)d_in[1];
    const float* bq = (const float*)d_in[2];
    const float* Wk = (const float*)d_in[3];
    const float* bk = (const float*)d_in[4];
    const float* Wv = (const float*)d_in[5];
    const float* bv = (const float*)d_in[6];
    const float* Wo = (const float*)d_in[7];
    const float* bo = (const float*)d_in[8];
    float* out = (float*)d_out;

    float* ws = (float*)d_ws;
    float* Q = ws;
    float* K = ws + (size_t)BT * HH;
    float* V = ws + (size_t)2 * BT * HH;
    float* O = ws + (size_t)3 * BT * HH;

    dim3 pgrid(BT / 64, 3);
    proj_kernel<<<pgrid, 256, 0, stream>>>(x, Wq, bq, Wk, bk, Wv, bv, Q, K, V);

    scan_kernel<<<BB, 512, 0, stream>>>(Q, K, V, O);

    dim3 ogrid(BT / 64, DD / 128);
    out_kernel<<<ogrid, 256, 0, stream>>>(O, Wo, bo, out);
}

// Round 3
// 1847.206 us; speedup vs baseline: 4.4392x; 1.7242x over previous
//
#include <hip/hip_runtime.h>
#include <math.h>

#define BB 4
#define TT 2048
#define DD 1024
#define HH 128
#define EPSF 1e-6f
#define BT (BB*TT)   // 8192

typedef float f32x2 __attribute__((ext_vector_type(2)));

// ---------------------------------------------------------------------------
// Projection: P[bt][h] = sum_d x[bt][d] * W[h][d] + bias[h]
// ---------------------------------------------------------------------------
__global__ __launch_bounds__(256) void proj_kernel(
    const float* __restrict__ x,
    const float* __restrict__ Wq, const float* __restrict__ bq,
    const float* __restrict__ Wk, const float* __restrict__ bk,
    const float* __restrict__ Wv, const float* __restrict__ bv,
    float* __restrict__ Q, float* __restrict__ K, float* __restrict__ V)
{
    const int which = blockIdx.y;
    const float* W    = (which == 0) ? Wq : (which == 1) ? Wk : Wv;
    const float* bias = (which == 0) ? bq : (which == 1) ? bk : bv;
    float* P          = (which == 0) ? Q  : (which == 1) ? K  : V;

    const int row0 = blockIdx.x * 64;

    __shared__ float xT[32][68];
    __shared__ float wT[32][132];

    const int tid = threadIdx.x;
    const int tx = tid & 15;
    const int ty = tid >> 4;

    float acc[4][8];
    #pragma unroll
    for (int i = 0; i < 4; i++)
        #pragma unroll
        for (int j = 0; j < 8; j++) acc[i][j] = 0.f;

    for (int k0 = 0; k0 < DD; k0 += 32) {
        #pragma unroll
        for (int l = 0; l < 2; l++) {
            int f = tid + l * 256;
            int r = f >> 3;
            int cg = f & 7;
            float4 v = *(const float4*)(x + (size_t)(row0 + r) * DD + k0 + cg * 4);
            xT[cg*4+0][r] = v.x; xT[cg*4+1][r] = v.y;
            xT[cg*4+2][r] = v.z; xT[cg*4+3][r] = v.w;
        }
        #pragma unroll
        for (int l = 0; l < 4; l++) {
            int f = tid + l * 256;
            int h = f >> 3;
            int cg = f & 7;
            float4 v = *(const float4*)(W + (size_t)h * DD + k0 + cg * 4);
            wT[cg*4+0][h] = v.x; wT[cg*4+1][h] = v.y;
            wT[cg*4+2][h] = v.z; wT[cg*4+3][h] = v.w;
        }
        __syncthreads();
        #pragma unroll
        for (int kk = 0; kk < 32; kk++) {
            float4 xv = *(const float4*)&xT[kk][ty * 4];
            float4 w0 = *(const float4*)&wT[kk][tx * 8];
            float4 w1 = *(const float4*)&wT[kk][tx * 8 + 4];
            float xa[4] = {xv.x, xv.y, xv.z, xv.w};
            float wa[8] = {w0.x, w0.y, w0.z, w0.w, w1.x, w1.y, w1.z, w1.w};
            #pragma unroll
            for (int i = 0; i < 4; i++)
                #pragma unroll
                for (int j = 0; j < 8; j++)
                    acc[i][j] += xa[i] * wa[j];
        }
        __syncthreads();
    }

    #pragma unroll
    for (int i = 0; i < 4; i++) {
        int row = row0 + ty * 4 + i;
        #pragma unroll
        for (int j = 0; j < 8; j++) acc[i][j] += bias[tx * 8 + j];
        float4 o0 = {acc[i][0], acc[i][1], acc[i][2], acc[i][3]};
        float4 o1 = {acc[i][4], acc[i][5], acc[i][6], acc[i][7]};
        *(float4*)(P + (size_t)row * HH + tx * 8)     = o0;
        *(float4*)(P + (size_t)row * HH + tx * 8 + 4) = o1;
    }
}

// ---------------------------------------------------------------------------
// Precompute per-step scalars: rns[row] = (1/(||k||+eps), k.q).
// These depend only on K,Q -> fully parallel, hoisted off the scan's
// critical path. One wave per row. Output lives in d_out (scratch until
// out_kernel runs).
// ---------------------------------------------------------------------------
__global__ __launch_bounds__(256) void rns_kernel(
    const float* __restrict__ K, const float* __restrict__ Q,
    float2* __restrict__ rns)
{
    const int row  = blockIdx.x * 4 + (threadIdx.x >> 6);
    const int lane = threadIdx.x & 63;
    const float* kp = K + (size_t)row * HH;
    const float* qp = Q + (size_t)row * HH;
    float k0 = kp[lane], k1 = kp[lane + 64];
    float q0 = qp[lane], q1 = qp[lane + 64];
    float p2  = k0 * k0 + k1 * k1;
    float pkq = k0 * q0 + k1 * q1;
    #pragma unroll
    for (int off = 32; off; off >>= 1) {
        p2  += __shfl_xor(p2, off);
        pkq += __shfl_xor(pkq, off);
    }
    if (lane == 0) {
        float rn = 1.0f / (sqrtf(p2) + EPSF);
        rns[row] = make_float2(rn, pkq);
    }
}

// quad butterfly sum via DPP (VALU, no DS pipe): returns sum over the 4
// lanes of the quad in all 4 lanes.
__device__ __forceinline__ float quad_red(float x) {
    x += __int_as_float(__builtin_amdgcn_mov_dpp(__float_as_int(x), 0xB1, 0xF, 0xF, true)); // quad_perm [1,0,3,2]
    x += __int_as_float(__builtin_amdgcn_mov_dpp(__float_as_int(x), 0x4E, 0xF, 0xF, true)); // quad_perm [2,3,0,1]
    return x;
}

// ---------------------------------------------------------------------------
// Sequential scan v4: issue-count-optimized.
// One barrier per step (v3 structure), plus:
//  - rn, s precomputed by rns_kernel (uniform per step, prefetched 1 step
//    ahead via a broadcast global load)
//  - packed f32x2 math (v_pk_fma_f32): praw 16, {pd,pq,Mq} 48, update 32
//  - DPP quad reductions instead of ds_bpermute shuffles
//  - o = (M_old q) + cM*(praw.q): only the A/M rank-1 update trails inv_d
// ---------------------------------------------------------------------------
__global__ __launch_bounds__(512, 1) void scan_kernel(
    const float* __restrict__ Q, const float* __restrict__ K,
    const float* __restrict__ V, const float2* __restrict__ rns,
    float* __restrict__ O)
{
    const int b   = blockIdx.x;
    const int tid = threadIdx.x;
    const int r   = tid >> 2;     // row 0..127
    const int q4  = tid & 3;      // column quarter
    const int c0  = q4 * 32;

    __shared__ float Aus[2][4 * 36];        // (A k) broadcast, padded
    __shared__ float kq[2][2][4 * 36];      // [buf][0=k,1=q], padded
    __shared__ float vbuf[2][128];          // v, linear

    f32x2 A2[16], M2[16];
    #pragma unroll
    for (int j = 0; j < 16; j++) {
        M2[j] = (f32x2){0.f, 0.f};
        A2[j].x = (c0 + 2 * j     == r) ? 1.0f : 0.0f;
        A2[j].y = (c0 + 2 * j + 1 == r) ? 1.0f : 0.0f;
    }

    const float* Qb = Q + (size_t)b * TT * HH;
    const float* Kb = K + (size_t)b * TT * HH;
    const float* Vb = V + (size_t)b * TT * HH;
    float*       Ob = O + (size_t)b * TT * HH;
    const float2* rns_b = rns + (size_t)b * TT;

    const int woff = (r >> 5) * 36 + (r & 31);   // my row's slot in Aus

    // loader role: 96 threads, one float4 each per step
    const bool ldr   = tid < 96;
    const int  which = tid >> 5;                 // 0=k 1=q 2=v
    const int  l32   = tid & 31;
    const float* src = (which == 0) ? Kb : (which == 1) ? Qb : Vb;
    const int  lpoff = (l32 >> 3) * 36 + (l32 & 7) * 4;  // padded f4 offset

    float4 pld = {0.f, 0.f, 0.f, 0.f};

    // prologue: stage t=0, prefetch t=1
    if (ldr) {
        float4 d0 = *(const float4*)(src + l32 * 4);
        if (which < 2) *(float4*)&kq[0][which][lpoff] = d0;
        else           *(float4*)&vbuf[0][l32 * 4]    = d0;
        pld = *(const float4*)(src + (size_t)HH + l32 * 4);
    }
    float2 rs_cur = rns_b[0];
    float2 rs_nxt = rns_b[1];
    __syncthreads();

    f32x2 kk2[16], qq2[16];
    #pragma unroll
    for (int j = 0; j < 8; j++) {
        float4 tk = *(const float4*)&kq[0][0][q4 * 36 + 4 * j];
        float4 tq = *(const float4*)&kq[0][1][q4 * 36 + 4 * j];
        kk2[2*j]   = (f32x2){tk.x, tk.y}; kk2[2*j+1] = (f32x2){tk.z, tk.w};
        qq2[2*j]   = (f32x2){tq.x, tq.y}; qq2[2*j+1] = (f32x2){tq.z, tq.w};
    }
    float vr = vbuf[0][r];

    for (int t = 0; t < TT; t++) {
        const int buf  = t & 1;
        const int nbuf = buf ^ 1;

        // --- praw = (A k)[r] partial over my 32 cols (packed)
        f32x2 pa0 = {0.f, 0.f}, pa1 = {0.f, 0.f};
        #pragma unroll
        for (int j = 0; j < 16; j += 2) {
            pa0 += A2[j]     * kk2[j];
            pa1 += A2[j + 1] * kk2[j + 1];
        }
        f32x2 pav = pa0 + pa1;
        float praw = quad_red(pav.x + pav.y);
        if (q4 == 0) Aus[buf][woff] = praw;

        // stage t+1 into LDS; issue global load for t+2
        if (ldr && t + 1 < TT) {
            if (which < 2) *(float4*)&kq[nbuf][which][lpoff] = pld;
            else           *(float4*)&vbuf[nbuf][l32 * 4]    = pld;
            if (t + 2 < TT)
                pld = *(const float4*)(src + (size_t)(t + 2) * HH + l32 * 4);
        }

        __syncthreads();   // the ONE barrier: Aus[buf] + kq/vbuf[nbuf] ready

        // --- read z~raw at my columns (conflict-free padded layout)
        f32x2 av2[16];
        #pragma unroll
        for (int j = 0; j < 8; j++) {
            float4 tv = *(const float4*)&Aus[buf][q4 * 36 + 4 * j];
            av2[2*j]   = (f32x2){tv.x, tv.y};
            av2[2*j+1] = (f32x2){tv.z, tv.w};
        }

        // --- three independent packed dots: pd = k.av, pq = q.av, x = (M q)
        f32x2 pdv = {0.f, 0.f}, pqv = {0.f, 0.f}, xv = {0.f, 0.f};
        #pragma unroll
        for (int j = 0; j < 16; j++) {
            f32x2 a = av2[j];
            pdv += a * kk2[j];
            pqv += a * qq2[j];
            xv  += M2[j] * qq2[j];
        }
        float pd = quad_red(pdv.x + pdv.y);
        float pq = quad_red(pqv.x + pqv.y);
        float x  = quad_red(xv.x + xv.y);

        const float rn  = rs_cur.x;
        const float s   = rs_cur.y;
        const float rn2 = rn * rn;
        const float inv_d = __builtin_amdgcn_rcpf(1.0f + rn2 * pd);
        const float cA = praw * rn2 * inv_d;      // A -= cA * praw_c
        const float cM = vr * s * rn * inv_d;     // M += cM * praw_c
        const float o  = x + cM * pq;             // (M_new q)[r]
        if (q4 == 0) Ob[(size_t)t * HH + r] = o;

        // --- rank-1 updates (only these trail inv_d)
        const f32x2 cAv = {cA, cA};
        const f32x2 cMv = {cM, cM};
        #pragma unroll
        for (int j = 0; j < 16; j++) {
            f32x2 a = av2[j];
            A2[j] -= cAv * a;
            M2[j] += cMv * a;
        }

        // --- refills for t+1 (dead registers, reads ordered vs writes by
        //     this step's barrier; next writes to these slots are at t+2,
        //     separated by barrier t+1)
        #pragma unroll
        for (int j = 0; j < 8; j++) {
            float4 tk = *(const float4*)&kq[nbuf][0][q4 * 36 + 4 * j];
            float4 tq = *(const float4*)&kq[nbuf][1][q4 * 36 + 4 * j];
            kk2[2*j]   = (f32x2){tk.x, tk.y}; kk2[2*j+1] = (f32x2){tk.z, tk.w};
            qq2[2*j]   = (f32x2){tq.x, tq.y}; qq2[2*j+1] = (f32x2){tq.z, tq.w};
        }
        vr = vbuf[nbuf][r];
        rs_cur = rs_nxt;
        if (t + 2 < TT) rs_nxt = rns_b[t + 2];
    }
}

// ---------------------------------------------------------------------------
// Output: out[bt][d] = sum_h O[bt][h] * Wo[d][h] + bo[d]
// ---------------------------------------------------------------------------
__global__ __launch_bounds__(256) void out_kernel(
    const float* __restrict__ O, const float* __restrict__ Wo,
    const float* __restrict__ bo, float* __restrict__ out)
{
    const int row0 = blockIdx.x * 64;
    const int d0   = blockIdx.y * 128;

    __shared__ float oT[32][68];
    __shared__ float woT[32][132];

    const int tid = threadIdx.x;
    const int tx = tid & 15;
    const int ty = tid >> 4;

    float acc[4][8];
    #pragma unroll
    for (int i = 0; i < 4; i++)
        #pragma unroll
        for (int j = 0; j < 8; j++) acc[i][j] = 0.f;

    for (int k0 = 0; k0 < HH; k0 += 32) {
        #pragma unroll
        for (int l = 0; l < 2; l++) {
            int f = tid + l * 256;
            int r = f >> 3;
            int cg = f & 7;
            float4 v = *(const float4*)(O + (size_t)(row0 + r) * HH + k0 + cg * 4);
            oT[cg*4+0][r] = v.x; oT[cg*4+1][r] = v.y;
            oT[cg*4+2][r] = v.z; oT[cg*4+3][r] = v.w;
        }
        #pragma unroll
        for (int l = 0; l < 4; l++) {
            int f = tid + l * 256;
            int d = f >> 3;
            int cg = f & 7;
            float4 v = *(const float4*)(Wo + (size_t)(d0 + d) * HH + k0 + cg * 4);
            woT[cg*4+0][d] = v.x; woT[cg*4+1][d] = v.y;
            woT[cg*4+2][d] = v.z; woT[cg*4+3][d] = v.w;
        }
        __syncthreads();
        #pragma unroll
        for (int kk = 0; kk < 32; kk++) {
            float4 ov = *(const float4*)&oT[kk][ty * 4];
            float4 w0 = *(const float4*)&woT[kk][tx * 8];
            float4 w1 = *(const float4*)&woT[kk][tx * 8 + 4];
            float oa[4] = {ov.x, ov.y, ov.z, ov.w};
            float wa[8] = {w0.x, w0.y, w0.z, w0.w, w1.x, w1.y, w1.z, w1.w};
            #pragma unroll
            for (int i = 0; i < 4; i++)
                #pragma unroll
                for (int j = 0; j < 8; j++)
                    acc[i][j] += oa[i] * wa[j];
        }
        __syncthreads();
    }

    #pragma unroll
    for (int i = 0; i < 4; i++) {
        int row = row0 + ty * 4 + i;
        #pragma unroll
        for (int j = 0; j < 8; j++) acc[i][j] += bo[d0 + tx * 8 + j];
        float4 o0 = {acc[i][0], acc[i][1], acc[i][2], acc[i][3]};
        float4 o1 = {acc[i][4], acc[i][5], acc[i][6], acc[i][7]};
        *(float4*)(out + (size_t)row * DD + d0 + tx * 8)     = o0;
        *(float4*)(out + (size_t)row * DD + d0 + tx * 8 + 4) = o1;
    }
}

extern "C" void kernel_launch(void* const* d_in, const int* in_sizes, int n_in,
                              void* d_out, int out_size, void* d_ws, size_t ws_size,
                              hipStream_t stream) {
    const float* x  = (const float*)d_in[0];
    const float* Wq = (const float*)d_in[1];
    const float* bq = (const float*)d_in[2];
    const float* Wk = (const float*)d_in[3];
    const float* bk = (const float*)d_in[4];
    const float* Wv = (const float*)d_in[5];
    const float* bv = (const float*)d_in[6];
    const float* Wo = (const float*)d_in[7];
    const float* bo = (const float*)d_in[8];
    float* out = (float*)d_out;

    float* ws = (float*)d_ws;
    float* Q = ws;
    float* K = ws + (size_t)BT * HH;
    float* V = ws + (size_t)2 * BT * HH;
    float* O = ws + (size_t)3 * BT * HH;
    // rns scalars live in d_out: it is scratch until out_kernel runs
    // (BT * 2 floats = 64 KB << out_size = 32 MB)
    float2* rns = (float2*)d_out;

    dim3 pgrid(BT / 64, 3);
    proj_kernel<<<pgrid, 256, 0, stream>>>(x, Wq, bq, Wk, bk, Wv, bv, Q, K, V);

    rns_kernel<<<BT / 4, 256, 0, stream>>>(K, Q, rns);

    scan_kernel<<<BB, 512, 0, stream>>>(Q, K, V, rns, O);

    dim3 ogrid(BT / 64, DD / 128);
    out_kernel<<<ogrid, 256, 0, stream>>>(O, Wo, bo, out);
}